// Round 9
// baseline (504.855 us; speedup 1.0000x reference)
//
#include <hip/hip_runtime.h>

#define TT 65536
#define R2 16384

typedef _Float16 f16x8 __attribute__((ext_vector_type(8)));
typedef float    f32x4 __attribute__((ext_vector_type(4)));
typedef unsigned u32x4 __attribute__((ext_vector_type(4)));

#define MFMA16 __builtin_amdgcn_mfma_f32_16x16x32_f16

// ---- helpers ----
__device__ __forceinline__ unsigned short f2h(float f){
    _Float16 h = (_Float16)f;
    return __builtin_bit_cast(unsigned short, h);
}
__device__ __forceinline__ float h2f(unsigned short u){
    return (float)__builtin_bit_cast(_Float16, u);
}
__device__ __forceinline__ unsigned relu2(unsigned w){
    unsigned s = w & 0x80008000u;
    unsigned mask = ((s >> 15) * 0x7FFFu) | s;
    return w & ~mask;
}
__device__ __forceinline__ float nrm(float a){
    float v = a / 1.101f + 0.5f;
    v = fmaxf(v, 0.0f);
    v = fminf(v, 0.99999f);
    return v;
}

// ---- repack weights f32 -> f16 B-fragment layout ----
__global__ __launch_bounds__(256) void k_repack(const float* __restrict__ W0,
        const float* __restrict__ W1, const float* __restrict__ Ws,
        const float* __restrict__ Wc, unsigned short* __restrict__ out){
    int e = blockIdx.x*256 + threadIdx.x;
    const float* src; int r;
    if (e < 409600){
        int i = e / 81920; r = e % 81920;
        if (r < 32768)      { src = W0 + (size_t)i*32768; }
        else if (r < 49152) { src = W1 + (size_t)i*16384; r -= 32768; }
        else                { src = Ws + (size_t)i*32768; r -= 49152; }
    } else { src = Wc; r = e - 409600; }
    int j = r & 7, l = (r >> 3) & 63, t = (r >> 9) & 7, ks = r >> 12;
    int k = ks*32 + (l >> 4)*8 + j;
    int n = t*16 + (l & 15);
    out[e] = f2h(src[k*128 + n]);
}

// ---- indices + histogram (fused) ----
__global__ __launch_bounds__(256) void k_idxhist(const float* __restrict__ p,
        int* __restrict__ idx, int* __restrict__ cnt){
    int pt = blockIdx.x*256 + threadIdx.x;
    float p0 = p[pt*3+0], p1 = p[pt*3+1], p2 = p[pt*3+2];
    int g0 = (int)(nrm(p0)*128.f);
    int g1 = (int)(nrm(p1)*128.f);
    int g2 = (int)(nrm(p2)*128.f);
    int i0 = g0 + 128*g2, i1 = g0 + 128*g1, i2 = g1 + 128*g2;
    idx[0*TT + pt] = i0;
    idx[1*TT + pt] = i1;
    idx[2*TT + pt] = i2;
    int b14 = (pt >> 15) << 14;
    atomicAdd(&cnt[0*32768 + b14 + i0], 1);
    atomicAdd(&cnt[1*32768 + b14 + i1], 1);
    atomicAdd(&cnt[2*32768 + b14 + i2], 1);
}

// ---- exclusive scan (1 block of 1024 per plane); cnt may alias cp ----
__global__ __launch_bounds__(1024) void k_scan(const int* __restrict__ cnt,
        int* __restrict__ cs, int* __restrict__ cp){
    __shared__ int ls[1024];
    int pl = blockIdx.x, tid = threadIdx.x;
    const int* c = cnt + pl*32768;
    int v[32], tot = 0;
    #pragma unroll
    for (int j = 0; j < 32; j++){ v[j] = c[tid*32 + j]; tot += v[j]; }
    int x = tot;
    ls[tid] = x; __syncthreads();
    for (int off = 1; off < 1024; off <<= 1){
        int add = (tid >= off) ? ls[tid - off] : 0;
        __syncthreads();
        x += add; ls[tid] = x;
        __syncthreads();
    }
    int run = x - tot;
    #pragma unroll
    for (int j = 0; j < 32; j++){
        cs[pl*32769 + tid*32 + j] = run;
        cp[pl*32768 + tid*32 + j] = run;
        run += v[j];
    }
    if (tid == 1023) cs[pl*32769 + 32768] = TT;
}

// ---- counting sort: scatter point ids ----
__global__ __launch_bounds__(256) void k_scatter(const int* __restrict__ idx,
        int* __restrict__ cp, int* __restrict__ srt){
    int pt = blockIdx.x*256 + threadIdx.x;
    int b14 = (pt >> 15) << 14;
    #pragma unroll
    for (int pl = 0; pl < 3; pl++){
        int pos = atomicAdd(&cp[pl*32768 + b14 + idx[pl*TT + pt]], 1);
        srt[pl*TT + pos] = pt;
    }
}

// ---- relabel points by plane-0 rank ----
__global__ __launch_bounds__(256) void k_remap1(const int* __restrict__ srt0,
        const int* __restrict__ idx, const float* __restrict__ p,
        int* __restrict__ idx2, float* __restrict__ pp, int* __restrict__ inv0){
    int pos = blockIdx.x*256 + threadIdx.x;
    int pt = srt0[pos];
    inv0[pt] = pos;
    idx2[0*TT + pos] = idx[0*TT + pt];
    idx2[1*TT + pos] = idx[1*TT + pt];
    idx2[2*TT + pos] = idx[2*TT + pt];
    pp[pos*3+0] = p[pt*3+0];
    pp[pos*3+1] = p[pt*3+1];
    pp[pos*3+2] = p[pt*3+2];
}
__global__ __launch_bounds__(256) void k_remap2(const int* __restrict__ srt,
        const int* __restrict__ inv0, int* __restrict__ srt2){
    int pos = blockIdx.x*256 + threadIdx.x;
    srt2[1*TT + pos] = inv0[srt[1*TT + pos]];
    srt2[2*TT + pos] = inv0[srt[2*TT + pos]];
}

// ---- pool: per-cell max -> mxp; plane 0 = linear row walk; 1 wave per block ----
__global__ __launch_bounds__(64) void k_pool_s(const unsigned short* __restrict__ nb,
        const int* __restrict__ srt, const int* __restrict__ cs,
        unsigned short* __restrict__ mxp){
    int lane = threadIdx.x;
    for (int cell = blockIdx.x; cell < 98304; cell += gridDim.x){
        int pl = cell >> 15, c = cell & 32767;
        int s = cs[pl*32769 + c], e = cs[pl*32769 + c + 1];
        if (s == e) continue;
        float mA = -1e30f, mB = -1e30f;
        if (pl == 0){
            for (int i = s; i < e; i++){
                unsigned v = ((const unsigned*)(nb + (size_t)i*128))[lane];
                mA = fmaxf(mA, h2f((unsigned short)(v & 0xFFFF)));
                mB = fmaxf(mB, h2f((unsigned short)(v >> 16)));
            }
        } else {
            const int* sp = srt + (size_t)pl*TT;
            int pt = sp[s];
            for (int i = s; i < e; i++){
                int ptn = (i+1 < e) ? sp[i+1] : 0;
                unsigned v = ((const unsigned*)(nb + (size_t)pt*128))[lane];
                mA = fmaxf(mA, h2f((unsigned short)(v & 0xFFFF)));
                mB = fmaxf(mB, h2f((unsigned short)(v >> 16)));
                pt = ptn;
            }
        }
        unsigned pk = (unsigned)f2h(mA) | ((unsigned)f2h(mB) << 16);
        ((unsigned*)(mxp + ((size_t)pl*32768 + c)*128))[lane] = pk;
    }
}

// ---- psum: scatter-mean + transpose -> out; plane 0 linear ----
__global__ __launch_bounds__(256, 4) void k_psum_s(const unsigned short* __restrict__ cb,
        const int* __restrict__ srt, const int* __restrict__ cs,
        float* __restrict__ out){
    __shared__ float ls[32*129];
    int tid = threadIdx.x, w = tid >> 6, lane = tid & 63;
    int t = blockIdx.x;                 // 0..3071
    int pl = t >> 10, c0 = (t & 1023)*32;
    #pragma unroll
    for (int cc = w; cc < 32; cc += 4){
        int s = cs[pl*32769 + c0 + cc], e = cs[pl*32769 + c0 + cc + 1];
        float s0 = 0.f, s1 = 0.f;
        if (s < e){
            if (pl == 0){
                for (int i = s; i < e; i++){
                    unsigned v = ((const unsigned*)(cb + (size_t)i*128))[lane];
                    s0 += h2f((unsigned short)(v & 0xFFFF));
                    s1 += h2f((unsigned short)(v >> 16));
                }
            } else {
                const int* sp = srt + (size_t)pl*TT;
                int pt = sp[s];
                for (int i = s; i < e; i++){
                    int ptn = (i+1 < e) ? sp[i+1] : 0;
                    unsigned v = ((const unsigned*)(cb + (size_t)pt*128))[lane];
                    s0 += h2f((unsigned short)(v & 0xFFFF));
                    s1 += h2f((unsigned short)(v >> 16));
                    pt = ptn;
                }
            }
        }
        float rc = (e > s) ? 1.f/(float)(e - s) : 0.f;
        ls[cc*129 + lane*2]     = s0*rc;
        ls[cc*129 + lane*2 + 1] = s1*rc;
    }
    __syncthreads();
    int pb = pl*2 + (c0 >> 14);
    float* o = out + (size_t)pb*128*R2 + (c0 & 16383);
    #pragma unroll
    for (int j = 0; j < 16; j++){
        int lin = j*256 + tid;          // lin = f*32 + cc
        int f = lin >> 5, cc = lin & 31;
        o[(size_t)f*R2 + cc] = ls[cc*129 + f];
    }
}

// one K=32 slab: prefetch next 8 B-frags while 16 MFMAs consume current 8
#define SEG(ACC, CURB, NEXTB, GETA)                                   \
  { _Pragma("unroll")                                                 \
    for (int ks = 0; ks < 4; ks++){                                   \
      f16x8* cur = (ks & 1) ? bq1 : bq0;                              \
      f16x8* nxt = (ks & 1) ? bq0 : bq1;                              \
      const unsigned short* nb_ = (ks < 3) ? (CURB) : (NEXTB);        \
      int nks = (ks < 3) ? ks + 1 : 0;                                \
      if (nb_) ld8(nxt, nb_, nks);                                    \
      f16x8 a0, a1;                                                   \
      GETA                                                            \
      _Pragma("unroll")                                               \
      for (int t = 0; t < 8; t++){                                    \
        ACC[0][t] = MFMA16(a0, cur[t], ACC[0][t], 0, 0, 0);           \
        ACC[1][t] = MFMA16(a1, cur[t], ACC[1][t], 0, 0, 0);           \
      }                                                               \
    }                                                                 \
  }

#define A_G1_XF { u32x4 u0 = get_xf(0, ks), u1 = get_xf(1, ks);                   \
    u0.x=relu2(u0.x); u0.y=relu2(u0.y); u0.z=relu2(u0.z); u0.w=relu2(u0.w);       \
    u1.x=relu2(u1.x); u1.y=relu2(u1.y); u1.z=relu2(u1.z); u1.w=relu2(u1.w);       \
    a0 = __builtin_bit_cast(f16x8, u0); a1 = __builtin_bit_cast(f16x8, u1); }
#define A_G1_PF { u32x4 u0 = __builtin_bit_cast(u32x4, pf[0][ks]);                \
    u32x4 u1 = __builtin_bit_cast(u32x4, pf[1][ks]);                              \
    u0.x=relu2(u0.x); u0.y=relu2(u0.y); u0.z=relu2(u0.z); u0.w=relu2(u0.w);       \
    u1.x=relu2(u1.x); u1.y=relu2(u1.y); u1.z=relu2(u1.z); u1.w=relu2(u1.w);       \
    a0 = __builtin_bit_cast(f16x8, u0); a1 = __builtin_bit_cast(f16x8, u1); }
#define A_G3_XF { a0 = __builtin_bit_cast(f16x8, get_xf(0, ks));                  \
                  a1 = __builtin_bit_cast(f16x8, get_xf(1, ks)); }
#define A_PF { a0 = pf[0][ks]; a1 = pf[1][ks]; }
#define A_LT { a0 = *(const f16x8*)&lt[((ks*8 + w*2 + 0)*64 + lane)*8];           \
               a1 = *(const f16x8*)&lt[((ks*8 + w*2 + 1)*64 + lane)*8]; }

// ---- fused ResnetBlockFC: barrier-free, B streamed from L2, x reloaded per use ----
__global__ __launch_bounds__(256, 3) void k_resnet_s(
        unsigned short* __restrict__ nb, unsigned short* __restrict__ cb,
        const unsigned short* __restrict__ wp,
        const float* __restrict__ b0, const float* __restrict__ b1,
        const int* __restrict__ idx, const unsigned short* __restrict__ mxp,
        const float* __restrict__ pin, const float* __restrict__ fW,
        const float* __restrict__ fb,
        const unsigned short* __restrict__ wc, const float* __restrict__ bc){
    __shared__ __align__(16) unsigned short lt[16384];   // 32 KB, wave-local strips
    int tid = threadIdx.x, w = tid >> 6, lane = tid & 63;
    int quad = lane >> 4, l15 = lane & 15;
    int m0 = blockIdx.x*128 + w*32;

    f16x8 bq0[8], bq1[8];
    auto ld8 = [&](f16x8* dst, const unsigned short* base, int ks){
        #pragma unroll
        for (int t = 0; t < 8; t++)
            dst[t] = *(const f16x8*)(base + ((size_t)((ks*8 + t)*64 + lane))*8);
    };
    ld8(bq0, wp, 0);   // first B window in flight during A setup

    float p0s[2], p1s[2], p2s[2];
    if (pin){
        #pragma unroll
        for (int s = 0; s < 2; s++){
            int row = m0 + s*16 + l15;
            p0s[s] = pin[row*3+0]; p1s[s] = pin[row*3+1]; p2s[s] = pin[row*3+2];
        }
    }
    // xf getter: recompute from p (pin) or reload nb row (x is f16-exact either way)
    auto get_xf = [&](int s, int ks)->u32x4 {
        if (pin){
            int c0 = ks*32 + quad*8;
            unsigned short hx[8];
            #pragma unroll
            for (int h = 0; h < 2; h++){
                f32x4 w0 = *(const f32x4*)(fW + c0 + h*4);
                f32x4 w1 = *(const f32x4*)(fW + 256 + c0 + h*4);
                f32x4 w2 = *(const f32x4*)(fW + 512 + c0 + h*4);
                f32x4 bb = *(const f32x4*)(fb + c0 + h*4);
                #pragma unroll
                for (int j = 0; j < 4; j++)
                    hx[h*4+j] = f2h(bb[j] + p0s[s]*w0[j] + p1s[s]*w1[j] + p2s[s]*w2[j]);
            }
            u32x4 r;
            unsigned short* d = (unsigned short*)&r;
            #pragma unroll
            for (int j = 0; j < 8; j++) d[j] = hx[j];
            return r;
        }
        return *(const u32x4*)(nb + (size_t)(m0 + s*16 + l15)*128 + ks*32 + quad*8);
    };

    // pooled half pf (cached; only 16 VGPRs)
    f16x8 pf[2][4];
    if (pin){
        #pragma unroll
        for (int s = 0; s < 2; s++){
            #pragma unroll
            for (int ks = 0; ks < 4; ks++){
                int c0 = 128 + ks*32 + quad*8;
                unsigned short hp[8];
                #pragma unroll
                for (int h = 0; h < 2; h++){
                    f32x4 v0 = *(const f32x4*)(fW + c0 + h*4);
                    f32x4 v1 = *(const f32x4*)(fW + 256 + c0 + h*4);
                    f32x4 v2 = *(const f32x4*)(fW + 512 + c0 + h*4);
                    f32x4 bp = *(const f32x4*)(fb + c0 + h*4);
                    #pragma unroll
                    for (int j = 0; j < 4; j++)
                        hp[h*4+j] = f2h(bp[j] + p0s[s]*v0[j] + p1s[s]*v1[j] + p2s[s]*v2[j]);
                }
                unsigned short* d = (unsigned short*)&pf[s][ks];
                #pragma unroll
                for (int j = 0; j < 8; j++) d[j] = hp[j];
            }
        }
    } else {
        #pragma unroll
        for (int s = 0; s < 2; s++){
            int row = m0 + s*16 + l15;
            int b14 = (row >> 15) << 14;
            const unsigned short* q0 = mxp + ((size_t)(0*32768 + b14 + idx[row]))*128;
            const unsigned short* q1 = mxp + ((size_t)(1*32768 + b14 + idx[TT + row]))*128;
            const unsigned short* q2 = mxp + ((size_t)(2*32768 + b14 + idx[2*TT + row]))*128;
            #pragma unroll
            for (int ks = 0; ks < 4; ks++){
                int col = ks*32 + quad*8;
                f16x8 a = *(const f16x8*)(q0 + col);
                f16x8 b = *(const f16x8*)(q1 + col);
                f16x8 c = *(const f16x8*)(q2 + col);
                f16x8 r;
                #pragma unroll
                for (int j = 0; j < 8; j++)
                    r[j] = (_Float16)((float)a[j] + (float)b[j] + (float)c[j]);
                pf[s][ks] = r;
            }
        }
    }

    f32x4 acc[2][8];
    #pragma unroll
    for (int s = 0; s < 2; s++)
        #pragma unroll
        for (int t = 0; t < 8; t++){ f32x4 z = {0.f,0.f,0.f,0.f}; acc[s][t] = z; }

    // GEMM1: relu(x) @ W0 (segments 0,1)
    SEG(acc, wp,         wp + 16384, A_G1_XF)
    SEG(acc, wp + 16384, wp + 32768, A_G1_PF)

    // transform relu(net+b0) -> lt (wave-local strips; no barrier)
    #pragma unroll
    for (int s = 0; s < 2; s++){
        int strip = w*2 + s;
        #pragma unroll
        for (int t = 0; t < 8; t++){
            float b0t = b0[t*16 + l15];
            int ks2 = t >> 1;
            int l2b = ((t & 1)*2 + ((lane >> 3) & 1))*16 + quad*4;
            #pragma unroll
            for (int r = 0; r < 4; r++){
                float v = acc[s][t][r] + b0t;
                v = fmaxf(v, 0.f);
                lt[(((ks2*8 + strip)*64) + l2b + r)*8 + (lane & 7)] = f2h(v);
            }
        }
    }

    // GEMM2: relu(net) @ W1 (segment 2), acc2 init b1
    f32x4 acc2[2][8];
    #pragma unroll
    for (int t = 0; t < 8; t++){
        float b1t = b1[t*16 + l15];
        f32x4 iv = {b1t, b1t, b1t, b1t};
        acc2[0][t] = iv; acc2[1][t] = iv;
    }
    SEG(acc2, wp + 32768, wp + 49152, A_LT)

    // GEMM3: shortcut x @ Ws (segments 3,4)
    SEG(acc2, wp + 49152, wp + 65536, A_G3_XF)
    SEG(acc2, wp + 65536, wc,         A_PF)

    if (!wc){
        #pragma unroll
        for (int s = 0; s < 2; s++)
            #pragma unroll
            for (int t = 0; t < 8; t++)
                #pragma unroll
                for (int r = 0; r < 4; r++){
                    int row = m0 + s*16 + quad*4 + r;
                    nb[(size_t)row*128 + t*16 + l15] = f2h(acc2[s][t][r]);
                }
        return;
    }

    // fused fc_c: net -> lt (no relu), GEMM (lt @ Wc) -> cb
    #pragma unroll
    for (int s = 0; s < 2; s++){
        int strip = w*2 + s;
        #pragma unroll
        for (int t = 0; t < 8; t++){
            int ks2 = t >> 1;
            int l2b = ((t & 1)*2 + ((lane >> 3) & 1))*16 + quad*4;
            #pragma unroll
            for (int r = 0; r < 4; r++)
                lt[(((ks2*8 + strip)*64) + l2b + r)*8 + (lane & 7)] = f2h(acc2[s][t][r]);
        }
    }
    f32x4 acc3[2][8];
    #pragma unroll
    for (int t = 0; t < 8; t++){
        float bv = bc[t*16 + l15];
        f32x4 iv = {bv, bv, bv, bv};
        acc3[0][t] = iv; acc3[1][t] = iv;
    }
    SEG(acc3, wc, (const unsigned short*)nullptr, A_LT)
    #pragma unroll
    for (int s = 0; s < 2; s++)
        #pragma unroll
        for (int t = 0; t < 8; t++)
            #pragma unroll
            for (int r = 0; r < 4; r++){
                int row = m0 + s*16 + quad*4 + r;
                cb[(size_t)row*128 + t*16 + l15] = f2h(acc3[s][t][r]);
            }
}

extern "C" void kernel_launch(void* const* d_in, const int* in_sizes, int n_in,
                              void* d_out, int out_size, void* d_ws, size_t ws_size,
                              hipStream_t stream) {
    const float* p        = (const float*)d_in[0];
    const float* fc_pos_W = (const float*)d_in[1];
    const float* fc_pos_b = (const float*)d_in[2];
    const float* bW0      = (const float*)d_in[3];
    const float* bb0      = (const float*)d_in[4];
    const float* bW1      = (const float*)d_in[5];
    const float* bb1      = (const float*)d_in[6];
    const float* bWs      = (const float*)d_in[7];
    const float* fc_c_W   = (const float*)d_in[8];
    const float* fc_c_b   = (const float*)d_in[9];
    float* out = (float*)d_out;

    char* ws = (char*)d_ws;
    int*            idx   = (int*)ws;                          // 786,432 B
    unsigned short* nb    = (unsigned short*)(ws + 786432);    // 16,777,216 B
    unsigned short* cb    = (unsigned short*)(ws + 17563648);  // 16,777,216 B
    int*            srt   = (int*)(ws + 34340864);             // 786,432 B
    int*            cs    = (int*)(ws + 35127296);             // 393,232 B
    int*            cp    = (int*)(ws + 35520528);             // 393,216 B
    unsigned short* wpack = (unsigned short*)(ws + 35913744);  // 851,968 B
    unsigned short* mxp   = (unsigned short*)(ws + 36765712);  // 25,165,824 B
    int*            idx2  = (int*)(ws + 61931536);             // 786,432 B
    float*          pp    = (float*)(ws + 62717968);           // 786,432 B
    int*            inv0  = (int*)(ws + 63504400);             // 262,144 B
    int*            srt2  = (int*)(ws + 63766544);             // 786,432 B

    k_repack<<<1664, 256, 0, stream>>>(bW0, bW1, bWs, fc_c_W, wpack);
    hipMemsetAsync(cp, 0, (size_t)3*32768*4, stream);
    k_idxhist<<<TT/256, 256, 0, stream>>>(p, idx, cp);
    k_scan   <<<3, 1024, 0, stream>>>(cp, cs, cp);
    k_scatter<<<TT/256, 256, 0, stream>>>(idx, cp, srt);
    k_remap1 <<<TT/256, 256, 0, stream>>>(srt, idx, p, idx2, pp, inv0);
    k_remap2 <<<TT/256, 256, 0, stream>>>(srt, inv0, srt2);

    // resnet 1: fc_pos fused (pin path)
    k_resnet_s<<<512, 256, 0, stream>>>(nb, cb, wpack, bb0, bb1,
            idx2, (const unsigned short*)nullptr,
            pp, fc_pos_W, fc_pos_b,
            (const unsigned short*)nullptr, (const float*)nullptr);

    for (int i = 1; i < 5; i++){
        k_pool_s<<<6144, 64, 0, stream>>>(nb, srt2, cs, mxp);
        const unsigned short* wc = (i == 4) ? (wpack + 409600) : (const unsigned short*)nullptr;
        const float* bcp = (i == 4) ? fc_c_b : (const float*)nullptr;
        k_resnet_s<<<512, 256, 0, stream>>>(nb, cb, wpack + (size_t)i*81920,
                bb0 + (size_t)i*128, bb1 + (size_t)i*128,
                idx2, mxp,
                (const float*)nullptr, (const float*)nullptr, (const float*)nullptr,
                wc, bcp);
    }

    k_psum_s<<<3072, 256, 0, stream>>>(cb, srt2, cs, out);
}